// Round 2
// baseline (982.876 us; speedup 1.0000x reference)
//
#include <hip/hip_runtime.h>
#include <hip/hip_bf16.h>

typedef unsigned short u16;
typedef float v4f __attribute__((ext_vector_type(4)));
typedef __bf16 v8bf __attribute__((ext_vector_type(8)));

constexpr int kP = 13;
constexpr int kD = 256;

__device__ __forceinline__ u16 f2u(float f){
  __bf16 b = (__bf16)f;
  return __builtin_bit_cast(u16, b);
}

// Prep: WqkT[c][d] = sum_e Wq[e,d]*Wk[e,c]   (= (Wq^T Wk)^T, stored so B-frags are contiguous in k)
//       Wvo [f][d] = sum_e Wo[f,e]*Wv[e,d]   (= Wo @ Wv, row-major, contiguous in k=d)
__global__ void lateral_prep(const float* __restrict__ Wq, const float* __restrict__ Wk,
                             const float* __restrict__ Wv, const float* __restrict__ Wo,
                             u16* __restrict__ wqkT, u16* __restrict__ wvo)
{
  const int c = blockIdx.x;   // 0..255
  const int d = threadIdx.x;  // 0..255
  float a1 = 0.f, a2 = 0.f;
  for (int e = 0; e < 256; ++e){
    a1 = fmaf(Wk[e*256 + c], Wq[e*256 + d], a1);  // broadcast * coalesced
    a2 = fmaf(Wo[c*256 + e], Wv[e*256 + d], a2);  // broadcast * coalesced
  }
  wqkT[c*256 + d] = f2u(a1);
  wvo [c*256 + d] = f2u(a2);
}

// Fused main: one wave per (b,t). Per-wave private 16x256 bf16 LDS tile, reused h -> g -> w.
// attn (16x16) parked in the tile's dead row 13 (bytes 6656..7167); w writes only rows<13 so it survives.
__global__ __launch_bounds__(512, 4)
void lateral_main(const float* __restrict__ hg, const float* __restrict__ Wlat,
                  const float* __restrict__ gate, const u16* __restrict__ wqkT,
                  const u16* __restrict__ wvo, float* __restrict__ out)
{
  __shared__ u16 lds[8*4096];           // 64 KiB: 8 waves x (16x256 bf16)
  const int lane = threadIdx.x & 63;
  const int wv   = threadIdx.x >> 6;
  const int g4   = lane >> 4;
  const int cl   = lane & 15;
  const long bt  = (long)blockIdx.x*8 + wv;      // 0..16383
  char* tile = reinterpret_cast<char*>(lds + wv*4096);
  const float* hb = hg + bt*(kP*kD);
  float* ob = out + bt*(kP*kD);

  const float sg = 1.f/(1.f + __expf(-gate[0]));

  // A-frag of W_lat^T: A[q=cl, p=g4*8+j] = Wlat[p, q]
  v8bf wlatf;
#pragma unroll
  for (int j=0;j<8;++j){
    const int p = g4*8 + j;
    const float v = (p < kP && cl < kP) ? Wlat[p*kP + cl] : 0.f;
    wlatf[j] = (__bf16)v;
  }

  // Phase 1: h -> LDS bf16, rows 13..15 zeroed, XOR-swizzled rows
#pragma unroll
  for (int r=0;r<16;++r){
    uint2 w2;
    if (r < kP){
      const float4 v = *reinterpret_cast<const float4*>(hb + r*kD + lane*4);
      w2.x = (unsigned)f2u(v.x) | ((unsigned)f2u(v.y) << 16);
      w2.y = (unsigned)f2u(v.z) | ((unsigned)f2u(v.w) << 16);
    } else { w2.x = 0u; w2.y = 0u; }
    const int a = (r*512 + lane*8) ^ ((r&7)<<4);
    *reinterpret_cast<uint2*>(tile + a) = w2;
  }

  // Phase 2: A-frags of h (lane: row=cl, k = kk*32 + g4*8 + j) — reused as A (g,w) and B (scores)
  v8bf ah[8];
#pragma unroll
  for (int kk=0;kk<8;++kk){
    const int a = (cl*512 + kk*64 + g4*16) ^ ((cl&7)<<4);
    ah[kk] = *reinterpret_cast<const v8bf*>(tile + a);
  }

  // Phase 3: g = h @ Wqk (B-frag: col c=WqkT row, contiguous k) -> overwrite tile (h dead in LDS)
#pragma unroll
  for (int n=0;n<16;++n){
    const int c = n*16 + cl;
    const u16* bp = wqkT + c*256;
    v4f acc = {0.f,0.f,0.f,0.f};
#pragma unroll
    for (int kk=0;kk<8;++kk){
      const v8bf bf = *reinterpret_cast<const v8bf*>(bp + kk*32 + g4*8);
      acc = __builtin_amdgcn_mfma_f32_16x16x32_bf16(ah[kk], bf, acc, 0, 0, 0);
    }
#pragma unroll
    for (int j=0;j<4;++j){
      const int r = g4*4 + j;                       // C layout: row=(lane>>4)*4+j, col=cl
      const int a = (r*512 + c*2) ^ ((r&7)<<4);
      *reinterpret_cast<u16*>(tile + a) = f2u(acc[j]);
    }
  }

  // Phase 4: scores = g @ h^T   (B-frag of h^T == A-frag of h)
  v4f sc = {0.f,0.f,0.f,0.f};
#pragma unroll
  for (int kk=0;kk<8;++kk){
    const int a = (cl*512 + kk*64 + g4*16) ^ ((cl&7)<<4);
    const v8bf ag = *reinterpret_cast<const v8bf*>(tile + a);
    sc = __builtin_amdgcn_mfma_f32_16x16x32_bf16(ag, ah[kk], sc, 0, 0, 0);
  }

  // Phase 5: softmax over cols (cl) within 16-lane groups; 4 independent rows per lane
  float att[4];
#pragma unroll
  for (int j=0;j<4;++j){
    const float s = (cl < kP) ? sc[j]*0.0625f : -INFINITY;   // scale = 1/sqrt(256)
    float m = s;
#pragma unroll
    for (int off=1; off<16; off<<=1) m = fmaxf(m, __shfl_xor(m, off, 64));
    const float e = (cl < kP) ? __expf(s - m) : 0.f;
    float sum = e;
#pragma unroll
    for (int off=1; off<16; off<<=1) sum += __shfl_xor(sum, off, 64);
    att[j] = e / sum;
  }
  // attn -> dead-row region (linear layout, bytes 6656..7167); cols>=13 are zeros
#pragma unroll
  for (int j=0;j<4;++j){
    const int r = g4*4 + j;
    *reinterpret_cast<u16*>(tile + (13*256 + r*16 + cl)*2) = f2u(att[j]);
  }

  // Phase 6: w = h @ Wvo^T (B-frag: col f=Wvo row, contiguous k=d); write rows<13 only
#pragma unroll
  for (int n=0;n<16;++n){
    const int c = n*16 + cl;
    const u16* bp = wvo + c*256;
    v4f acc = {0.f,0.f,0.f,0.f};
#pragma unroll
    for (int kk=0;kk<8;++kk){
      const v8bf bf = *reinterpret_cast<const v8bf*>(bp + kk*32 + g4*8);
      acc = __builtin_amdgcn_mfma_f32_16x16x32_bf16(ah[kk], bf, acc, 0, 0, 0);
    }
#pragma unroll
    for (int j=0;j<4;++j){
      const int r = g4*4 + j;
      if (r < kP){
        const int a = (r*512 + c*2) ^ ((r&7)<<4);
        *reinterpret_cast<u16*>(tile + a) = f2u(acc[j]);
      }
    }
  }

  // attn A-frag: A[p=cl, q=g4*8+j]; k>=16 lanes are zero (attn cols 13..15 stored as 0)
  v8bf attf;
  if (g4 < 2){
    attf = *reinterpret_cast<const v8bf*>(tile + (13*256 + cl*16 + g4*8)*2);
  } else {
#pragma unroll
    for (int j=0;j<8;++j) attf[j] = (__bf16)0.f;
  }

  // Phase 7: epilogue per 16-col tile: out = residual(W_lat^T @ h) + sg * (attn @ w)
#pragma unroll
  for (int n=0;n<16;++n){
    const int cc = n*16 + cl;
    // B-frag from w columns (scalar LDS reads; rows 13..15 hit attn junk but x0 via attf)
    v8bf wf;
#pragma unroll
    for (int j=0;j<8;++j){
      const int k = g4*8 + j;
      u16 u = 0;
      if (k < 16){
        const int a = (k*512 + cc*2) ^ ((k&7)<<4);
        u = *reinterpret_cast<const u16*>(tile + a);
      }
      wf[j] = __builtin_bit_cast(__bf16, u);
    }
    v4f r = {0.f,0.f,0.f,0.f};
    r = __builtin_amdgcn_mfma_f32_16x16x32_bf16(attf, wf, r, 0, 0, 0);
#pragma unroll
    for (int j=0;j<4;++j) r[j] *= sg;
    // residual B-frag: h columns straight from global (L1/L2-warm), cvt to bf16
    v8bf hf;
#pragma unroll
    for (int j=0;j<8;++j){
      const int k = g4*8 + j;
      const float v = (k < kP) ? hb[k*kD + cc] : 0.f;
      hf[j] = (__bf16)v;
    }
    r = __builtin_amdgcn_mfma_f32_16x16x32_bf16(wlatf, hf, r, 0, 0, 0);
#pragma unroll
    for (int j=0;j<4;++j){
      const int p = g4*4 + j;
      if (p < kP) ob[p*kD + cc] = r[j];
    }
  }
}

extern "C" void kernel_launch(void* const* d_in, const int* in_sizes, int n_in,
                              void* d_out, int out_size, void* d_ws, size_t ws_size,
                              hipStream_t stream)
{
  const float* h    = (const float*)d_in[0];
  const float* Wq   = (const float*)d_in[1];
  const float* Wk   = (const float*)d_in[2];
  const float* Wv   = (const float*)d_in[3];
  const float* Wo   = (const float*)d_in[4];
  const float* Wlat = (const float*)d_in[5];
  const float* gate = (const float*)d_in[6];
  float* out = (float*)d_out;

  u16* wqkT = (u16*)d_ws;            // 65536 bf16 = 128 KiB
  u16* wvo  = wqkT + 65536;          // +128 KiB (ws usage: 256 KiB)

  lateral_prep<<<256, 256, 0, stream>>>(Wq, Wk, Wv, Wo, wqkT, wvo);
  lateral_main<<<2048, 512, 0, stream>>>(h, Wlat, gate, wqkT, wvo, out);
}